// Round 4
// baseline (9914.920 us; speedup 1.0000x reference)
//
#include <hip/hip_runtime.h>

typedef _Float16 f16;
typedef _Float16 half8 __attribute__((ext_vector_type(8)));
typedef float f32x4 __attribute__((ext_vector_type(4)));
typedef float f32x2 __attribute__((ext_vector_type(2)));

#define TT 512
#define HID 1024

__device__ __forceinline__ half8 cvt8(f32x4 lo, f32x4 hi) {
  half8 r;
  r[0]=(f16)lo[0]; r[1]=(f16)lo[1]; r[2]=(f16)lo[2]; r[3]=(f16)lo[3];
  r[4]=(f16)hi[0]; r[5]=(f16)hi[1]; r[6]=(f16)hi[2]; r[7]=(f16)hi[3];
  return r;
}
// device-scope coherent ops: write through / read past L2 (never flush caches)
__device__ __forceinline__ void st_sc_u32(unsigned* p, unsigned v) {
  asm volatile("global_store_dword %0, %1, off sc0 sc1" :: "v"(p), "v"(v) : "memory");
}
__device__ __forceinline__ unsigned ld_sc_u32(const unsigned* p) {
  unsigned v;
  asm volatile("global_load_dword %0, %1, off sc0 sc1\n\ts_waitcnt vmcnt(0)"
               : "=v"(v) : "v"(p) : "memory");
  return v;
}
__device__ __forceinline__ void atom_inc_sc(unsigned* p) {
  unsigned one = 1u;
  asm volatile("global_atomic_add %0, %1, off sc1" :: "v"(p), "v"(one) : "memory");
}
__device__ __forceinline__ void pollFlag(const unsigned* p) {
  int gd = 0;
  while (ld_sc_u32(p) < 64u) { __builtin_amdgcn_s_sleep(1); if (++gd > (1<<20)) break; }
}
#define LGKM0_BARRIER() do { asm volatile("s_waitcnt lgkmcnt(0)" ::: "memory"); \
                             __builtin_amdgcn_s_barrier(); } while(0)

// x f32 -> f16 (layout kept [B][T][D])
__global__ void init_misc(const float* __restrict__ x, f16* __restrict__ xh) {
  size_t i = ((size_t)blockIdx.x*256 + threadIdx.x)*8;
  f32x4 a = *(const f32x4*)(x+i);
  f32x4 b = *(const f32x4*)(x+i+4);
  *(half8*)(xh+i) = cvt8(a,b);
}

// Persistent pipelined TSGRU. 256 WGs x 512 thr (8 waves). WG = (layer, 16 cols).
// Wave (g,kq): W[g][3 gates][16 cols][K-slot kq] persistent in 96 VGPRs.
// Per step: all staging loads issued at top (rolling 2-quarter reg window),
// 4 quarter barriers, 24 MFMA/wave/quarter, col-major padded PART reduce, fp32 gates.
__global__ __launch_bounds__(512, 2) void tsgru_k(
    const float* __restrict__ dtp,
    const float* __restrict__ Wih, const float* __restrict__ Whh,
    const float* __restrict__ bih, const float* __restrict__ bhh,
    const float* __restrict__ tau, const f16* __restrict__ xh,
    f16* __restrict__ H, f16* __restrict__ HD3,
    unsigned* __restrict__ flags, float* __restrict__ out) {
  extern __shared__ char lds[];
  float* nLo  = (float*)lds;            // [4][32][4] f32 (cols 8u..8u+3 of quarter)
  float* nHi  = (float*)(lds + 2048);   // [4][32][4] f32 (cols 8u+4..8u+7)
  float* nG   = (float*)(lds + 4096);   // [1024] plain copy for gate
  float* bias = (float*)(lds + 8192);   // [6][16]
  char*  Abase = lds + 12288;           // Ag q&1 @ +0/+32768 ; Ah q&1 @ +65536/+98304
  float* PART = (float*)(lds + 12288);  // alias; [2g*4kq*3q][16 col][68 rows] f32

  const int tid = threadIdx.x, lane = tid & 63, wv = tid >> 6;
  const int g = wv >> 2, kq = wv & 3;
  const int wg = blockIdx.x, layer = wg >> 6, wgl = wg & 63, col0 = wgl * 16;
  const int gb = tid >> 3, gc2 = (tid & 7) * 2;
  const int su = lane & 31;

  // ---- persistent weights in VGPRs (f32 source, convert inline)
  const float* Wsrc = (g ? Whh : Wih) + (size_t)layer*3072*HID;
  const int wrow = col0 + (lane & 15);
  const int kfr = kq*32 + ((lane>>4)&3)*8;
  half8 bW[3][8];
  #pragma unroll
  for (int q=0;q<3;q++)
    #pragma unroll
    for (int kc=0;kc<8;kc++) {
      const float* p = Wsrc + (size_t)(q*HID + wrow)*HID + kc*128 + kfr;
      bW[q][kc] = cvt8(*(const f32x4*)p, *(const f32x4*)(p+4));
    }

  // ---- nitau (split lo/hi for conflict-free f32x4 reads) + gate copy + biases
  for (int c = tid; c < HID; c += 512) {
    float v = -1.0f / log1pf(expf(tau[layer*HID + c]));
    nG[c] = v;
    int q = c >> 8, r = c & 255, u = r >> 3, j = r & 7;
    if (j < 4) nLo[q*128 + u*4 + j] = v; else nHi[q*128 + u*4 + (j-4)] = v;
  }
  if (tid < 96) {
    int j = tid >> 4, c = tid & 15;
    bias[j*16 + c] = (j < 3) ? bih[layer*3072 + j*HID + col0 + c]
                             : bhh[layer*3072 + (j-3)*HID + col0 + c];
  }
  __syncthreads();

  const f16* agB0; size_t agRS;
  if (layer == 0) { agB0 = xh; agRS = (size_t)TT*HID; }
  else            { agB0 = H + (size_t)(layer-1)*TT*65536; agRS = (size_t)HID; }
  const f16* Hl = H + (size_t)layer*TT*65536;     // own h plane (layers 0-2 only)
  unsigned* flagOwn = flags + layer*TT;
  unsigned* flagUp  = flags + (layer > 0 ? layer-1 : 0)*TT;

  float hdv0 = 0.f, hdv1 = 0.f;

  for (int t = 0; t < TT; ++t) {
    // ---- prefetch read-only scalars (before polls; inputs are flag-independent)
    float dts0=0,dts1=0,dts2=0,dts3=0;
    if (layer < 3) {
      dts0 = dtp[(wv*8 + 0 + (lane>>5))*TT + t];
      dts1 = dtp[(wv*8 + 2 + (lane>>5))*TT + t];
      dts2 = dtp[(wv*8 + 4 + (lane>>5))*TT + t];
      dts3 = dtp[(wv*8 + 6 + (lane>>5))*TT + t];
    }
    float dtg1 = (t < TT-1) ? dtp[gb*TT + t + 1] : 0.f;

    // ---- point-to-point waits (single counter per (layer,t), all lanes broadcast-poll)
    if (t > 0) pollFlag(flagOwn + (t-1));
    if (layer > 0) pollFlag(flagUp + t);

    const f16* agT = (layer == 0) ? agB0 + (size_t)t*HID : agB0 + (size_t)t*65536;
    const f16* ahT = (layer == 3) ? HD3 + (size_t)t*65536
                                  : Hl + (size_t)(t > 0 ? t-1 : 0)*65536;
    const bool ahLoad = (layer == 3) || (t > 0);

    half8 rg[2][4], rh[2][4];
    auto issueQ = [&](int q) {
      const int qo = q*256 + su*8;
      #pragma unroll
      for (int i=0;i<4;i++) {
        int row = wv*8 + 2*i + (lane>>5);
        rg[q&1][i] = *(const half8*)(agT + (size_t)row*agRS + qo);
        if (ahLoad) rh[q&1][i] = *(const half8*)(ahT + (size_t)row*HID + qo);
      }
    };
    auto writeQ = [&](int q) {
      char* Agb = Abase + (q&1)*32768;
      char* Ahb = Abase + 65536 + (q&1)*32768;
      #pragma unroll
      for (int i=0;i<4;i++) {
        int row = wv*8 + 2*i + (lane>>5);
        int off = row*512 + ((su ^ (row&7))*16);
        *(half8*)(Agb + off) = rg[q&1][i];
        half8 hv;
        if (layer == 3) {
          hv = rh[q&1][i];
        } else if (t == 0) {
          for (int j=0;j<8;j++) hv[j] = (f16)0.f;
        } else {
          f32x4 nl = *(const f32x4*)(nLo + q*128 + su*4);
          f32x4 nh = *(const f32x4*)(nHi + q*128 + su*4);
          float dtv = (i==0)?dts0:(i==1)?dts1:(i==2)?dts2:dts3;
          #pragma unroll
          for (int j=0;j<4;j++) {
            hv[j]   = (f16)((float)rh[q&1][i][j]   * __expf(dtv*nl[j]));
            hv[4+j] = (f16)((float)rh[q&1][i][4+j] * __expf(dtv*nh[j]));
          }
        }
        *(half8*)(Ahb + off) = hv;
      }
    };

    issueQ(0); issueQ(1);

    f32x4 acc[4][3];
    #pragma unroll
    for (int m=0;m<4;m++)
      #pragma unroll
      for (int q=0;q<3;q++) acc[m][q] = (f32x4){0.f,0.f,0.f,0.f};

    #pragma unroll
    for (int q=0;q<4;q++) {
      writeQ(q);
      if (q < 2) issueQ(q+2);       // rolling window; loads fly across barriers
      LGKM0_BARRIER();              // quarter q staged by all waves
      const char* Ab = Abase + (g ? 65536 : 0) + (q&1)*32768;
      #pragma unroll
      for (int kcq=0;kcq<2;kcq++) {
        const int ub = kcq*16 + kq*4 + ((lane>>4)&3);
        const int kc = q*2 + kcq;
        #pragma unroll
        for (int m=0;m<4;m++) {
          int row = m*16 + (lane&15);
          half8 aF = *(const half8*)(Ab + row*512 + ((ub ^ (row&7))*16));
          acc[m][0] = __builtin_amdgcn_mfma_f32_16x16x32_f16(aF, bW[0][kc], acc[m][0], 0,0,0);
          acc[m][1] = __builtin_amdgcn_mfma_f32_16x16x32_f16(aF, bW[1][kc], acc[m][1], 0,0,0);
          acc[m][2] = __builtin_amdgcn_mfma_f32_16x16x32_f16(aF, bW[2][kc], acc[m][2], 0,0,0);
        }
      }
    }
    LGKM0_BARRIER();   // all A-reads done -> PART may overwrite aliased buffers

    // ---- partials, col-major pad-68: optimal-bank b128 stores of 4 batch rows
    {
      float* Pb = PART + (size_t)((g*4 + kq)*3)*1088 + (lane&15)*68 + ((lane>>4)&3)*4;
      #pragma unroll
      for (int qg=0;qg<3;qg++)
        #pragma unroll
        for (int m=0;m<4;m++)
          *(f32x4*)(Pb + qg*1088 + m*16) = acc[m][qg];
    }
    LGKM0_BARRIER();

    // ---- gates: thread -> (batch gb, cols gc2,gc2+1), fp32 math, hd kept in regs
    {
      float hv_0, hv_1, hdn_0, hdn_1;
      #pragma unroll
      for (int e=0;e<2;e++) {
        const int c = gc2 + e;
        const int pb = c*68 + gb;
        float sx0=0,sx1=0,sx2=0,sh0=0,sh1=0,sh2=0;
        #pragma unroll
        for (int k2=0;k2<4;k2++) {
          const float* Px = PART + (size_t)(k2*3)*1088 + pb;
          sx0 += Px[0]; sx1 += Px[1088]; sx2 += Px[2176];
          const float* Ph = PART + (size_t)((4+k2)*3)*1088 + pb;
          sh0 += Ph[0]; sh1 += Ph[1088]; sh2 += Ph[2176];
        }
        const float hdv = e ? hdv1 : hdv0;
        const float rgt = 1.f/(1.f + __expf(-(sx0 + bias[c]      + sh0 + bias[48+c])));
        const float zgt = 1.f/(1.f + __expf(-(sx1 + bias[16+c]   + sh1 + bias[64+c])));
        const float ngt = tanhf(sx2 + bias[32+c] + rgt*(sh2 + bias[80+c]));
        const float hv = (1.f - zgt)*ngt + zgt*hdv;
        const float hdn = (t < TT-1) ? hv * __expf(dtg1 * nG[col0 + c]) : 0.f;
        if (e) { hv_1 = hv; hdn_1 = hdn; hdv1 = hdn; }
        else   { hv_0 = hv; hdn_0 = hdn; hdv0 = hdn; }
      }
      union { f16 h[2]; unsigned u; } pk;
      if (layer < 3) {
        pk.h[0] = (f16)hv_0; pk.h[1] = (f16)hv_1;
        st_sc_u32((unsigned*)(H + ((size_t)layer*TT + t)*65536 + gb*HID + col0 + gc2), pk.u);
      } else {
        f32x2 v; v[0] = hv_0; v[1] = hv_1;
        *(f32x2*)(out + ((size_t)gb*TT + t)*HID + col0 + gc2) = v;
        if (t < TT-1) {
          pk.h[0] = (f16)hdn_0; pk.h[1] = (f16)hdn_1;
          st_sc_u32((unsigned*)(HD3 + (size_t)(t+1)*65536 + gb*HID + col0 + gc2), pk.u);
        }
      }
    }
    asm volatile("s_waitcnt vmcnt(0) lgkmcnt(0)" ::: "memory");  // stores at coherent point
    __builtin_amdgcn_s_barrier();
    if (tid == 0) atom_inc_sc(flagOwn + t);
  }
}

extern "C" void kernel_launch(void* const* d_in, const int* in_sizes, int n_in,
                              void* d_out, int out_size, void* d_ws, size_t ws_size,
                              hipStream_t stream) {
  const float* x   = (const float*)d_in[0];
  const float* dtp = (const float*)d_in[1];
  const float* Wih = (const float*)d_in[2];
  const float* Whh = (const float*)d_in[3];
  const float* bih = (const float*)d_in[4];
  const float* bhh = (const float*)d_in[5];
  const float* tau = (const float*)d_in[6];
  float* out = (float*)d_out;
  char* ws = (char*)d_ws;

  // ws: xh [64][512][1024] f16 (67,108,864) | H [3][512][64][1024] f16 (201,326,592)
  //   | HD3 [512][64][1024] f16 (67,108,864) | flags [4][512] u32 (8192) = 335,552,512 B
  f16* xh  = (f16*)ws;
  f16* H   = (f16*)(ws + 67108864);
  f16* HD3 = (f16*)(ws + 268435456);
  unsigned* flags = (unsigned*)(ws + 335544320);

  hipMemsetAsync(flags, 0, 8192, stream);
  hipMemsetAsync(HD3, 0, 131072, stream);          // hd[layer3][t=0] = 0
  init_misc<<<16384, 256, 0, stream>>>(x, xh);
  const int ldsBytes = 143360;                     // >80KB -> 1 WG/CU, grid=256=CUs
  hipFuncSetAttribute((const void*)tsgru_k, hipFuncAttributeMaxDynamicSharedMemorySize, ldsBytes);
  tsgru_k<<<256, 512, ldsBytes, stream>>>(dtp, Wih, Whh, bih, bhh, tau, xh, H, HD3, flags, out);
}

// Round 5
// 4928.366 us; speedup vs baseline: 2.0118x; 2.0118x over previous
//
#include <hip/hip_runtime.h>

typedef _Float16 f16;
typedef _Float16 half8 __attribute__((ext_vector_type(8)));
typedef float f32x4 __attribute__((ext_vector_type(4)));
typedef float f32x2 __attribute__((ext_vector_type(2)));

#define TT 512
#define HID 1024

// async global->LDS, 16B/lane; LDS dest = wave-uniform base + lane*16 (linear)
#define GLOAD_LDS16(gp, lp) \
  __builtin_amdgcn_global_load_lds((const __attribute__((address_space(1))) void*)(gp), \
                                   (__attribute__((address_space(3))) void*)(lp), 16, 0, 0)

__device__ __forceinline__ half8 cvt8(f32x4 lo, f32x4 hi) {
  half8 r;
  r[0]=(f16)lo[0]; r[1]=(f16)lo[1]; r[2]=(f16)lo[2]; r[3]=(f16)lo[3];
  r[4]=(f16)hi[0]; r[5]=(f16)hi[1]; r[6]=(f16)hi[2]; r[7]=(f16)hi[3];
  return r;
}
// device-scope coherent ops: write through / read past L2 (never flush caches)
__device__ __forceinline__ void st_sc_u32(unsigned* p, unsigned v) {
  asm volatile("global_store_dword %0, %1, off sc0 sc1" :: "v"(p), "v"(v) : "memory");
}
__device__ __forceinline__ unsigned ld_sc_u32(const unsigned* p) {
  unsigned v;
  asm volatile("global_load_dword %0, %1, off sc0 sc1\n\ts_waitcnt vmcnt(0)"
               : "=v"(v) : "v"(p) : "memory");
  return v;
}
__device__ __forceinline__ void spinFlag(const unsigned* p) {
  int gd = 0;
  while (ld_sc_u32(p) == 0u) { __builtin_amdgcn_s_sleep(1); if (++gd > (1<<20)) break; }
}
__device__ __forceinline__ float sigm(float x)  { return 1.f/(1.f + __expf(-x)); }
__device__ __forceinline__ float ftanh(float x) { return 1.f - 2.f/(1.f + __expf(2.f*x)); }

// x f32 -> f16 (layout kept [B][T][D])
__global__ void init_misc(const float* __restrict__ x, f16* __restrict__ xh) {
  size_t i = ((size_t)blockIdx.x*256 + threadIdx.x)*8;
  f32x4 a = *(const f32x4*)(x+i);
  f32x4 b = *(const f32x4*)(x+i+4);
  *(half8*)(xh+i) = cvt8(a,b);
}

// Persistent pipelined TSGRU. 256 WGs x 512 thr (8 waves). WG = (layer, 16 cols).
// Wave (g,kq): W[g][3 gates][16 cols][K-slot kq] persistent in 96 VGPRs.
// Staging = PURE COPY via global_load_lds (source cols pre-swizzled so the
// linear LDS write realizes the XOR layout). hd is precomputed by the gate of
// step t-1 into ping-pong plane HD[l][t&1] (so no decay math in staging).
// K split in 4 quarters, 2-buffer ping-pong, counted vmcnt(8) (never drained
// mid-pipe). Per-WG flags, all waves poll.
__global__ __launch_bounds__(512, 2) void tsgru_k(
    const float* __restrict__ dtp, const float* __restrict__ Wih,
    const float* __restrict__ Whh, const float* __restrict__ bih,
    const float* __restrict__ bhh, const float* __restrict__ tau,
    const f16* __restrict__ xh, f16* __restrict__ H, f16* __restrict__ HD,
    unsigned* __restrict__ flags, float* __restrict__ out) {
  extern __shared__ char lds[];
  // Ag0 @0, Ag1 @32768, Ah0 @65536, Ah1 @98304 (32KB each, [64 rows][512B] XOR-swz)
  // PART [24 slices][1088 f32] (104448B) aliases @0, barrier-separated
  float* PART = (float*)lds;

  const int tid = threadIdx.x, lane = tid & 63, wv = tid >> 6;
  const int g = wv >> 2, kq = wv & 3;
  const int wg = blockIdx.x, layer = wg >> 6, wgl = wg & 63, col0 = wgl*16;
  const int l5 = lane >> 5, su = lane & 31;

  // ---- persistent weights in VGPRs (f32 source, convert inline; read once)
  const float* Wsrc = (g ? Whh : Wih) + (size_t)layer*3072*HID;
  const int wrow = col0 + (lane & 15);
  const int kfr = kq*32 + ((lane>>4)&3)*8;
  half8 bW[3][8];
  #pragma unroll
  for (int q=0;q<3;q++)
    #pragma unroll
    for (int kc=0;kc<8;kc++) {
      const float* p = Wsrc + (size_t)(q*HID + wrow)*HID + kc*128 + kfr;
      bW[q][kc] = cvt8(*(const f32x4*)p, *(const f32x4*)(p+4));
    }

  // ---- gate constants in registers
  const int gb = tid >> 3, gc2 = (tid & 7)*2;
  float biR[2],biZ[2],biN[2],bhR[2],bhZ[2],bhN[2],ni[2];
  #pragma unroll
  for (int e=0;e<2;e++) {
    const int c = col0 + gc2 + e;
    biR[e]=bih[layer*3072+c]; biZ[e]=bih[layer*3072+1024+c]; biN[e]=bih[layer*3072+2048+c];
    bhR[e]=bhh[layer*3072+c]; bhZ[e]=bhh[layer*3072+1024+c]; bhN[e]=bhh[layer*3072+2048+c];
    ni[e] = -1.0f / log1pf(expf(tau[layer*HID + c]));
  }

  const f16* agB; size_t agRS;
  if (layer == 0) { agB = xh; agRS = (size_t)TT*HID; }
  else            { agB = H + (size_t)(layer-1)*TT*65536; agRS = (size_t)HID; }
  f16* HDl = HD + (size_t)layer*2*65536;
  unsigned* flagOwn = flags + (size_t)layer*TT*64;
  const unsigned* flagUp = flags + (size_t)(layer>0 ? layer-1 : 0)*TT*64;

  float hdv0 = 0.f, hdv1 = 0.f;

  for (int t = 0; t < TT; ++t) {
    const float dtg1 = (t < TT-1) ? dtp[gb*TT + t + 1] : 0.f;

    // ---- per-WG flags; every wave polls (own WG's flag trivially satisfied)
    if (t > 0 && lane != wgl) spinFlag(flagOwn + (size_t)(t-1)*64 + lane);
    if (layer > 0)            spinFlag(flagUp  + (size_t)t*64 + lane);

    const f16* agT = (layer==0) ? agB + (size_t)t*HID : agB + (size_t)t*65536;
    const f16* ahT = HDl + (size_t)(t & 1)*65536;

    auto issueQ = [&](int q, int par) {
      const int qo = q*256;
      #pragma unroll
      for (int i=0;i<4;i++) {
        const int b  = wv*8 + 2*i + l5;                 // global batch row
        const int sw = (su ^ (2*i + l5)) * 8;           // pre-swizzled col (f16)
        char* ld0 = lds + par*32768 + (wv*8 + 2*i)*512; // wave-uniform LDS base
        GLOAD_LDS16(agT + (size_t)b*agRS + qo + sw, ld0);
        GLOAD_LDS16(ahT + (size_t)b*HID  + qo + sw, ld0 + 65536);
      }
    };

    issueQ(0,0); issueQ(1,1);                       // 16 loads in flight
    asm volatile("s_waitcnt vmcnt(8)" ::: "memory");// Q0 resident (mine)
    __builtin_amdgcn_s_barrier();                   // Q0 resident (all waves)

    f32x4 acc[4][3];
    #pragma unroll
    for (int m=0;m<4;m++) { acc[m][0]=(f32x4){0.f,0.f,0.f,0.f}; acc[m][1]=acc[m][0]; acc[m][2]=acc[m][0]; }

    const char* AbB = lds + (g ? 65536 : 0);
    #pragma unroll
    for (int q=0;q<4;q++) {
      const char* Ab = AbB + (q&1)*32768;
      #pragma unroll
      for (int kcq=0;kcq<2;kcq++) {
        const int ub = kcq*16 + kq*4 + ((lane>>4)&3);
        const int kc = q*2 + kcq;
        #pragma unroll
        for (int m=0;m<4;m++) {
          const int row = m*16 + (lane&15);
          const half8 aF = *(const half8*)(Ab + row*512 + ((ub ^ (row&7))*16));
          acc[m][0] = __builtin_amdgcn_mfma_f32_16x16x32_f16(aF, bW[0][kc], acc[m][0],0,0,0);
          acc[m][1] = __builtin_amdgcn_mfma_f32_16x16x32_f16(aF, bW[1][kc], acc[m][1],0,0,0);
          acc[m][2] = __builtin_amdgcn_mfma_f32_16x16x32_f16(aF, bW[2][kc], acc[m][2],0,0,0);
        }
      }
      if (q < 2) {
        __builtin_amdgcn_s_barrier();                   // all waves done reading buf q&1
        issueQ(q+2, q&1);
        asm volatile("s_waitcnt vmcnt(8)" ::: "memory");// Q(q+1) resident (mine)
        __builtin_amdgcn_s_barrier();                   // ... (all waves)
      } else if (q == 2) {
        asm volatile("s_waitcnt vmcnt(0)" ::: "memory");// Q3 resident
        __builtin_amdgcn_s_barrier();
      }
    }
    __builtin_amdgcn_s_barrier();   // all A-reads done -> PART may alias bufs

    // ---- partial sums, col-major pad-68 (bank-friendly b128 stores)
    {
      float* Pb = PART + (size_t)((g*4+kq)*3)*1088 + (lane&15)*68 + ((lane>>4)&3)*4;
      #pragma unroll
      for (int qg=0;qg<3;qg++)
        #pragma unroll
        for (int m=0;m<4;m++)
          *(f32x4*)(Pb + qg*1088 + m*16) = acc[m][qg];
    }
    asm volatile("s_waitcnt lgkmcnt(0)" ::: "memory");
    __builtin_amdgcn_s_barrier();

    // ---- gates: thread -> (batch gb, cols gc2,gc2+1); hd kept in regs + HD plane
    {
      float hv[2];
      #pragma unroll
      for (int e=0;e<2;e++) {
        const int pb = (gc2+e)*68 + gb;
        float sx0=0,sx1=0,sx2=0,sh0=0,sh1=0,sh2=0;
        #pragma unroll
        for (int k2=0;k2<4;k2++) {
          const float* Px = PART + (size_t)(k2*3)*1088 + pb;
          sx0 += Px[0]; sx1 += Px[1088]; sx2 += Px[2176];
          const float* Ph = PART + (size_t)((4+k2)*3)*1088 + pb;
          sh0 += Ph[0]; sh1 += Ph[1088]; sh2 += Ph[2176];
        }
        const float hdv = e ? hdv1 : hdv0;
        const float r = sigm(sx0 + biR[e] + sh0 + bhR[e]);
        const float z = sigm(sx1 + biZ[e] + sh1 + bhZ[e]);
        const float n = ftanh(sx2 + biN[e] + r*(sh2 + bhN[e]));
        hv[e] = (1.f - z)*n + z*hdv;
      }
      union { f16 h[2]; unsigned u; } pk;
      if (layer < 3) {
        pk.h[0]=(f16)hv[0]; pk.h[1]=(f16)hv[1];
        st_sc_u32((unsigned*)(H + ((size_t)layer*TT + t)*65536 + gb*HID + col0 + gc2), pk.u);
      } else {
        f32x2 v; v[0]=hv[0]; v[1]=hv[1];
        *(f32x2*)(out + ((size_t)gb*TT + t)*HID + col0 + gc2) = v;
      }
      if (t < TT-1) {
        const float hd0 = hv[0]*__expf(dtg1*ni[0]);
        const float hd1 = hv[1]*__expf(dtg1*ni[1]);
        pk.h[0]=(f16)hd0; pk.h[1]=(f16)hd1;
        st_sc_u32((unsigned*)(HDl + (size_t)((t+1)&1)*65536 + gb*HID + col0 + gc2), pk.u);
        hdv0 = hd0; hdv1 = hd1;
      }
    }
    asm volatile("s_waitcnt vmcnt(0) lgkmcnt(0)" ::: "memory");  // stores coherent
    __builtin_amdgcn_s_barrier();
    if (tid == 0) st_sc_u32(flagOwn + (size_t)t*64 + wgl, 1u);
  }
}

extern "C" void kernel_launch(void* const* d_in, const int* in_sizes, int n_in,
                              void* d_out, int out_size, void* d_ws, size_t ws_size,
                              hipStream_t stream) {
  const float* x   = (const float*)d_in[0];
  const float* dtp = (const float*)d_in[1];
  const float* Wih = (const float*)d_in[2];
  const float* Whh = (const float*)d_in[3];
  const float* bih = (const float*)d_in[4];
  const float* bhh = (const float*)d_in[5];
  const float* tau = (const float*)d_in[6];
  float* out = (float*)d_out;
  char* ws = (char*)d_ws;

  // ws: xh [64][512][1024] f16 (67,108,864) | H [3][512][64][1024] f16 (201,326,592)
  //   | HD [4][2][64][1024] f16 (1,048,576) | flags [4][512][64] u32 (524,288)
  //   -> total 270,008,320 B
  f16* xh = (f16*)ws;
  f16* H  = (f16*)(ws + 67108864);
  f16* HD = (f16*)(ws + 268435456);
  unsigned* flags = (unsigned*)(ws + 269484032);

  (void)hipMemsetAsync(flags, 0, 524288, stream);
  (void)hipMemsetAsync(HD, 0, 1048576, stream);     // hd[l][t=0] = 0
  init_misc<<<16384, 256, 0, stream>>>(x, xh);
  const int ldsBytes = 131072;                      // >80KB -> 1 WG/CU, grid=256=CUs
  (void)hipFuncSetAttribute((const void*)tsgru_k, hipFuncAttributeMaxDynamicSharedMemorySize, ldsBytes);
  tsgru_k<<<256, 512, ldsBytes, stream>>>(dtp, Wih, Whh, bih, bhh, tau, xh, H, HD, flags, out);
}